// Round 13
// baseline (254.489 us; speedup 1.0000x reference)
//
#include <hip/hip_runtime.h>
#include <hip/hip_bf16.h>

#define N_NODES 50000
#define N_EDGES 800000
#define DIM 128
#define NTILES (N_EDGES / 64)   // 12500 exactly
#define NODE_B 782              // ceil(50000/64)
#define CNT_B 256               // count blocks (LDS hist, no atomics)
#define OUTZ_B 512
#define NBIN 196                // ceil(50000/256) coarse buckets (dst>>8)
#define E_PER_CBLK 3125         // 800000/256
#define CAP 7680                // per-bucket LDS sort capacity (mean 4096, +56 sigma)

typedef __bf16 bf16x8 __attribute__((ext_vector_type(8)));
typedef float f32x4 __attribute__((ext_vector_type(4)));
typedef unsigned int u32x4 __attribute__((ext_vector_type(4)));
typedef short s16x2 __attribute__((ext_vector_type(2)));

__device__ __forceinline__ unsigned short f2bf(float f) {
    unsigned u = __float_as_uint(f);
    u += 0x7fffu + ((u >> 16) & 1u);          // round-to-nearest-even
    return (unsigned short)(u >> 16);
}
__device__ __forceinline__ unsigned short f2bf_hw(float f) {
    __hip_bfloat16 h = __float2bfloat16(f);
    unsigned short s;
    __builtin_memcpy(&s, &h, 2);
    return s;
}
// packed bf16x2 add (v_pk_add_bf16 on gfx950) + relu via packed int16 max
__device__ __forceinline__ unsigned bf2_add_relu(unsigned a, unsigned b) {
    __hip_bfloat162 A, B;
    __builtin_memcpy(&A, &a, 4);
    __builtin_memcpy(&B, &b, 4);
    __hip_bfloat162 S = __hadd2(A, B);
    unsigned s;
    __builtin_memcpy(&s, &S, 4);
    s16x2 sv = __builtin_bit_cast(s16x2, s);
    s16x2 z = (s16x2){0, 0};
    return __builtin_bit_cast(unsigned, __builtin_elementwise_max(sv, z));
}

// ---- K1 (R19-proven): weights (blocks 0..255) + LDS coarse count (256..511) + zero out.
__global__ __launch_bounds__(256) void setup_kernel(
        const float* __restrict__ W1, const float* __restrict__ W2,
        const float* __restrict__ W3, const int* __restrict__ eidx,
        unsigned short* __restrict__ W1t, unsigned short* __restrict__ Wat,
        unsigned short* __restrict__ Wbt, unsigned short* __restrict__ W3t,
        int* __restrict__ counts, u32x4* __restrict__ outz) {
    __shared__ int hh[256];
    int bid = blockIdx.x, tid = threadIdx.x;
    if (bid < 256) {
        int i = bid * 256 + tid;
        int j = i & (DIM * DIM - 1);
        int k = j >> 7, n = j & 127;
        int sec = i >> 14;
        if (sec == 0)      W1t[n * 128 + k] = f2bf(W1[k * 128 + n]);
        else if (sec == 1) Wat[n * 128 + k] = f2bf(W2[k * 128 + n] - W2[(k + 128) * 128 + n]);
        else if (sec == 2) Wbt[n * 128 + k] = f2bf(W2[(k + 128) * 128 + n]);
        else               W3t[n * 128 + k] = f2bf(W3[k * 128 + n]);
    } else if (bid < 512) {
        int cblk = bid - 256;
        hh[tid] = 0;
        __syncthreads();
        int base = cblk * E_PER_CBLK;
        #pragma unroll
        for (int i = 0; i < 13; i++) {
            int idx = i * 256 + tid;
            if (idx < E_PER_CBLK)
                atomicAdd(&hh[eidx[N_EDGES + base + idx] >> 8], 1);
        }
        __syncthreads();
        counts[tid * 256 + cblk] = hh[tid];     // [bin][block]
    } else {
        int b = bid - 512;
        u32x4 z = (u32x4){0u, 0u, 0u, 0u};
        for (int i = b * 256 + tid; i < N_NODES * DIM / 4; i += OUTZ_B * 256) outz[i] = z;
    }
}

// ---- K2 (R18-proven): per-bin exclusive scan over blocks + bin totals.
__global__ void scanA_kernel(int* __restrict__ counts, int* __restrict__ binsum) {
    __shared__ int buf[256];
    int tid = threadIdx.x, b = blockIdx.x;   // b = bin
    int v = counts[b * 256 + tid];
    buf[tid] = v;
    __syncthreads();
    for (int off = 1; off < 256; off <<= 1) {
        int u = (tid >= off) ? buf[tid - off] : 0;
        __syncthreads();
        buf[tid] += u;
        __syncthreads();
    }
    counts[b * 256 + tid] = buf[tid] - v;     // exclusive prefix over blocks
    if (tid == 255) binsum[b] = buf[255];
}

// ---- K3 (R19-proven): node GEMM (blocks 0..781) overlapped with coarse
// scatter (blocks 782..1037). Zero global atomics in scatter.
__global__ __launch_bounds__(256, 2) void gemm_scatter_kernel(
        const int* __restrict__ eidx, const int* __restrict__ counts,
        const int* __restrict__ binsum,
        const float* __restrict__ x, const unsigned short* __restrict__ W1t,
        const unsigned short* __restrict__ Wat, const unsigned short* __restrict__ Wbt,
        const float* __restrict__ b1, const float* __restrict__ b2,
        unsigned short* __restrict__ gA, unsigned short* __restrict__ gB,
        int2* __restrict__ spair) {
    __shared__ __align__(16) unsigned short w1t[128 * 136];
    __shared__ __align__(16) unsigned short h_lds[64 * 136];
    int tid = threadIdx.x, bid = blockIdx.x;

    if (bid >= NODE_B) {
        // ---- coarse scatter into dst>>8 buckets, LDS cursors only
        int blk = bid - NODE_B;
        int* lds = (int*)w1t;                 // [0..255]=scan buf, [256..511]=cursors
        int v = (tid < NBIN) ? binsum[tid] : 0;
        lds[tid] = v;
        __syncthreads();
        for (int off = 1; off < 256; off <<= 1) {
            int u = (tid >= off) ? lds[tid - off] : 0;
            __syncthreads();
            lds[tid] += u;
            __syncthreads();
        }
        int bb = lds[tid] - v;                // exclusive binbase
        __syncthreads();
        lds[256 + tid] = bb + ((tid < NBIN) ? counts[tid * 256 + blk] : 0);
        __syncthreads();
        int* lcur = lds + 256;
        int base = blk * E_PER_CBLK;
        #pragma unroll
        for (int i = 0; i < 13; i++) {
            int idx = i * 256 + tid;
            if (idx < E_PER_CBLK) {
                int e = base + idx;
                int d = eidx[N_EDGES + e];
                int s = eidx[e];
                int p = atomicAdd(&lcur[d >> 8], 1);   // LDS atomic
                spair[p] = make_int2(s, d);
            }
        }
        return;
    }

    // ---- node GEMM (R12-proven): h = bf16(x@W1+b1) -> LDS -> gA, gB
    int bl = bid;
    #pragma unroll
    for (int it = 0; it < 8; it++) {
        int idx = (tid + it * 256) * 8;
        int n = idx >> 7, k = idx & 127;
        *(u32x4*)(&w1t[n * 136 + k]) = *(const u32x4*)(&W1t[idx]);
    }
    int w = tid >> 6, lane = tid & 63;
    int lr = lane & 15, q = lane >> 4;
    bf16x8 baf[2][4], bbf[2][4];
    float b2v[2];
    #pragma unroll
    for (int ct = 0; ct < 2; ct++) {
        int n = (2 * w + ct) * 16 + lr;
        #pragma unroll
        for (int kt = 0; kt < 4; kt++) {
            baf[ct][kt] = __builtin_bit_cast(bf16x8, *(const u32x4*)(&Wat[n * 128 + kt * 32 + q * 8]));
            bbf[ct][kt] = __builtin_bit_cast(bf16x8, *(const u32x4*)(&Wbt[n * 128 + kt * 32 + q * 8]));
        }
        b2v[ct] = b2[n];
    }
    __syncthreads();
    int row0 = bl * 64;
    int rowA = row0 + w * 16 + lr; if (rowA >= N_NODES) rowA = N_NODES - 1;
    {
        f32x4 acc[8];
        #pragma unroll
        for (int ct = 0; ct < 8; ct++) acc[ct] = (f32x4){0.f, 0.f, 0.f, 0.f};
        #pragma unroll
        for (int kt = 0; kt < 4; kt++) {
            const float* ap = x + (size_t)rowA * DIM + kt * 32 + q * 8;
            f32x4 x0 = *(const f32x4*)(ap);
            f32x4 x1 = *(const f32x4*)(ap + 4);
            bf16x8 a;
            #pragma unroll
            for (int j = 0; j < 4; j++) { a[j] = (__bf16)x0[j]; a[j + 4] = (__bf16)x1[j]; }
            #pragma unroll
            for (int ct = 0; ct < 8; ct++) {
                bf16x8 b = __builtin_bit_cast(bf16x8,
                    *(const u32x4*)(&w1t[(ct * 16 + lr) * 136 + kt * 32 + q * 8]));
                acc[ct] = __builtin_amdgcn_mfma_f32_16x16x32_bf16(a, b, acc[ct], 0, 0, 0);
            }
        }
        #pragma unroll
        for (int ct = 0; ct < 8; ct++) {
            int col = ct * 16 + lr;
            float bias = b1[col];
            #pragma unroll
            for (int r = 0; r < 4; r++)   // C/D: col=lane&15, row=quad*4+reg
                h_lds[(w * 16 + q * 4 + r) * 136 + col] = f2bf(acc[ct][r] + bias);
        }
    }
    __syncthreads();
    {
        f32x4 accA[4][2], accB[4][2];
        #pragma unroll
        for (int rt = 0; rt < 4; rt++)
            #pragma unroll
            for (int ct = 0; ct < 2; ct++) {
                accA[rt][ct] = (f32x4){0.f, 0.f, 0.f, 0.f};
                accB[rt][ct] = (f32x4){0.f, 0.f, 0.f, 0.f};
            }
        #pragma unroll
        for (int kt = 0; kt < 4; kt++) {
            #pragma unroll
            for (int rt = 0; rt < 4; rt++) {
                bf16x8 a = __builtin_bit_cast(bf16x8,
                    *(const u32x4*)(&h_lds[(rt * 16 + lr) * 136 + kt * 32 + q * 8]));
                accA[rt][0] = __builtin_amdgcn_mfma_f32_16x16x32_bf16(a, baf[0][kt], accA[rt][0], 0, 0, 0);
                accA[rt][1] = __builtin_amdgcn_mfma_f32_16x16x32_bf16(a, baf[1][kt], accA[rt][1], 0, 0, 0);
                accB[rt][0] = __builtin_amdgcn_mfma_f32_16x16x32_bf16(a, bbf[0][kt], accB[rt][0], 0, 0, 0);
                accB[rt][1] = __builtin_amdgcn_mfma_f32_16x16x32_bf16(a, bbf[1][kt], accB[rt][1], 0, 0, 0);
            }
        }
        #pragma unroll
        for (int rt = 0; rt < 4; rt++) {
            #pragma unroll
            for (int ct = 0; ct < 2; ct++) {
                int col = (2 * w + ct) * 16 + lr;
                #pragma unroll
                for (int r = 0; r < 4; r++) {
                    int row = row0 + rt * 16 + q * 4 + r;
                    if (row < N_NODES) {
                        gA[(size_t)row * DIM + col] = f2bf(accA[rt][ct][r] + b2v[ct]);
                        gB[(size_t)row * DIM + col] = f2bf(accB[rt][ct][r]);
                    }
                }
            }
        }
    }
}

// ---- K4 (R19-proven): per-bucket LDS sort by dst&255, local binbase from binsum.
__global__ __launch_bounds__(256) void bsort_kernel(
        const int* __restrict__ binsum, int2* __restrict__ spair) {
    __shared__ int2 el[CAP];
    __shared__ int h[256];
    __shared__ int cum[256];
    __shared__ int bb[257];
    int tid = threadIdx.x, b = blockIdx.x;
    int v = (tid < NBIN) ? binsum[tid] : 0;
    cum[tid] = v;
    __syncthreads();
    for (int off = 1; off < 256; off <<= 1) {
        int u = (tid >= off) ? cum[tid - off] : 0;
        __syncthreads();
        cum[tid] += u;
        __syncthreads();
    }
    bb[tid] = cum[tid] - v;
    if (tid == 255) bb[256] = cum[255];
    __syncthreads();

    int start = bb[b];
    int n = bb[b + 1] - start;
    int nn = (n < CAP) ? n : CAP;
    for (int i = tid; i < nn; i += 256) el[i] = spair[start + i];
    h[tid] = 0;
    __syncthreads();
    for (int i = tid; i < nn; i += 256) atomicAdd(&h[el[i].y & 255], 1);
    __syncthreads();
    int v2 = h[tid];
    cum[tid] = v2;
    __syncthreads();
    for (int off = 1; off < 256; off <<= 1) {
        int u = (tid >= off) ? cum[tid - off] : 0;
        __syncthreads();
        cum[tid] += u;
        __syncthreads();
    }
    cum[tid] -= v2;                           // exclusive
    __syncthreads();
    for (int i = tid; i < nn; i += 256) {
        int2 e = el[i];
        int p = start + atomicAdd(&cum[e.y & 255], 1);
        spair[p] = e;
    }
}

// ---- K5 (R22): 1-barrier edge kernel with wave-local segmax — R21 + the fix.
// R21's NaN: removing barrier(2) also removed the COMPILER fence that ordered
// the ushort m2 stores before the cross-type (unsigned*) segmax loads; TBAA
// let the compiler hoist the loads -> uninitialized reads. Fix: a zero-cost
// compiler fence (asm "memory" clobber) between m2 writes and segmax reads.
// HW side is already safe: same-wave DS ops execute in order, and m2 cols are
// wave-private; s_dst/m1 are double-buffered (skew bounded by barrier (1)).
__global__ __launch_bounds__(256, 3) void edge_kernel(
        const unsigned short* __restrict__ gA,
        const unsigned short* __restrict__ gB,
        const int2* __restrict__ spair,
        const unsigned short* __restrict__ W3t,
        const float* __restrict__ b3,
        unsigned int* __restrict__ out) {
    __shared__ __align__(16) unsigned short m1_lds[2][64 * 136];
    __shared__ __align__(16) unsigned short m2_lds[64 * 136];
    __shared__ int s_dst[2][64];

    int tid = threadIdx.x;
    int w = tid >> 6, lane = tid & 63;
    int lr = lane & 15, q = lane >> 4;
    int tr = tid >> 4;
    int c = (tid & 15) * 8;

    bf16x8 b3f[2][4];
    float b3v[2];
    #pragma unroll
    for (int ct = 0; ct < 2; ct++) {
        int n = (2 * w + ct) * 16 + lr;
        #pragma unroll
        for (int kt = 0; kt < 4; kt++)
            b3f[ct][kt] = __builtin_bit_cast(bf16x8, *(const u32x4*)(&W3t[n * 128 + kt * 32 + q * 8]));
        b3v[ct] = b3[n];
    }

    const int G = (int)gridDim.x;
    int tb = blockIdx.x;
    int sel = 0;

    int2 pcur[4];
    u32x4 gb_r[4];
    {
        int eb = tb * 64;
        #pragma unroll
        for (int it = 0; it < 4; it++) pcur[it] = spair[eb + tr + 16 * it];
        #pragma unroll
        for (int it = 0; it < 4; it++)
            gb_r[it] = *(const u32x4*)(&gB[(size_t)pcur[it].x * DIM + c]);
    }

    for (; tb < NTILES; tb += G) {
        #pragma unroll
        for (int it = 0; it < 4; it++) {
            int t = tr + 16 * it;
            u32x4 ga = *(const u32x4*)(&gA[(size_t)pcur[it].y * DIM + c]);
            u32x4 m;
            #pragma unroll
            for (int jj = 0; jj < 4; jj++)
                m[jj] = bf2_add_relu(ga[jj], gb_r[it][jj]);
            *(u32x4*)(&m1_lds[sel][t * 136 + c]) = m;
        }
        if ((tid & 15) == 0) {
            #pragma unroll
            for (int it = 0; it < 4; it++) s_dst[sel][tr + 16 * it] = pcur[it].y;
        }
        __syncthreads();   // (1) m1[sel] + s_dst[sel] ready — the ONLY barrier per iter

        int nx = tb + G;
        int2 pnx[4];
        if (nx < NTILES) {
            int eb = nx * 64;
            #pragma unroll
            for (int it = 0; it < 4; it++) pnx[it] = spair[eb + tr + 16 * it];
            #pragma unroll
            for (int it = 0; it < 4; it++)
                gb_r[it] = *(const u32x4*)(&gB[(size_t)pnx[it].x * DIM + c]);
        }

        f32x4 acc2[4][2];
        #pragma unroll
        for (int rt = 0; rt < 4; rt++)
            #pragma unroll
            for (int ct = 0; ct < 2; ct++) acc2[rt][ct] = (f32x4){0.f, 0.f, 0.f, 0.f};
        #pragma unroll
        for (int kt = 0; kt < 4; kt++) {
            #pragma unroll
            for (int rt = 0; rt < 4; rt++) {
                bf16x8 a = __builtin_bit_cast(bf16x8,
                    *(const u32x4*)(&m1_lds[sel][(rt * 16 + lr) * 136 + kt * 32 + q * 8]));
                acc2[rt][0] = __builtin_amdgcn_mfma_f32_16x16x32_bf16(a, b3f[0][kt], acc2[rt][0], 0, 0, 0);
                acc2[rt][1] = __builtin_amdgcn_mfma_f32_16x16x32_bf16(a, b3f[1][kt], acc2[rt][1], 0, 0, 0);
            }
        }
        // m2 write: wave w's own cols [32w, 32w+32) — private region, no barrier
        #pragma unroll
        for (int rt = 0; rt < 4; rt++) {
            #pragma unroll
            for (int ct = 0; ct < 2; ct++) {
                int col = (2 * w + ct) * 16 + lr;
                #pragma unroll
                for (int r = 0; r < 4; r++)
                    m2_lds[(rt * 16 + q * 4 + r) * 136 + col] = f2bf_hw(fmaxf(acc2[rt][ct][r] + b3v[ct], 0.f));
            }
        }
        // COMPILER fence: forbid hoisting the (cross-type) segmax LDS loads above
        // the m2 stores. No instruction emitted; same-wave DS ops are in-order in HW.
        asm volatile("" ::: "memory");
        // segmax: wave-local — lane -> (col pair = w*16 + (lane>>2), 16-row group = lane&3).
        {
            int pair = w * 16 + (lane >> 2);
            int g2 = lane & 3;
            const unsigned* m2p = (const unsigned*)m2_lds;   // [64][68] dwords
            int r0 = g2 * 16;
            unsigned cur = m2p[r0 * 68 + pair];
            int d = s_dst[sel][r0];
            bool first = true;                          // first segment may extend before r0
            #pragma unroll 4
            for (int i = 1; i < 16; i++) {
                int dn = s_dst[sel][r0 + i];
                unsigned v = m2p[(r0 + i) * 68 + pair];
                if (dn != d) {
                    if (first) {
                        atomicMax(&out[(size_t)d * DIM + 2 * pair],     (cur & 0xffffu) << 16);
                        atomicMax(&out[(size_t)d * DIM + 2 * pair + 1], cur & 0xffff0000u);
                    } else {
                        // interior segment: unique writer -> plain coalesced 8B store
                        uint2 st = make_uint2((cur & 0xffffu) << 16, cur & 0xffff0000u);
                        *(uint2*)(&out[(size_t)d * DIM + 2 * pair]) = st;
                    }
                    first = false;
                    d = dn; cur = v;
                } else {
                    s16x2 a2 = __builtin_bit_cast(s16x2, cur);
                    s16x2 b2 = __builtin_bit_cast(s16x2, v);
                    cur = __builtin_bit_cast(unsigned, __builtin_elementwise_max(a2, b2));
                }
            }
            // last segment may extend past r0+15 -> always atomic
            atomicMax(&out[(size_t)d * DIM + 2 * pair],     (cur & 0xffffu) << 16);
            atomicMax(&out[(size_t)d * DIM + 2 * pair + 1], cur & 0xffff0000u);
        }
        // no trailing barrier: m1 double-buffered (fast wave writes m1[sel^1]),
        // m2 cols are wave-private, s_dst double-buffered.

        sel ^= 1;
        #pragma unroll
        for (int it = 0; it < 4; it++) pcur[it] = pnx[it];
    }
}

extern "C" void kernel_launch(void* const* d_in, const int* in_sizes, int n_in,
                              void* d_out, int out_size, void* d_ws, size_t ws_size,
                              hipStream_t stream) {
    const float* x  = (const float*)d_in[0];
    const int* eidx = (const int*)d_in[1];
    const float* W1 = (const float*)d_in[2];
    const float* b1 = (const float*)d_in[3];
    const float* W2 = (const float*)d_in[4];
    const float* b2 = (const float*)d_in[5];
    const float* W3 = (const float*)d_in[6];
    const float* b3 = (const float*)d_in[7];

    char* ws = (char*)d_ws;
    unsigned short* gA  = (unsigned short*)ws;                     // 12,800,000 B
    unsigned short* gB  = (unsigned short*)(ws + 12800000);        // 12,800,000 B
    unsigned short* W1t = (unsigned short*)(ws + 25600000);        // 32,768 B
    unsigned short* Wat = (unsigned short*)(ws + 25632768);        // 32,768 B
    unsigned short* Wbt = (unsigned short*)(ws + 25665536);        // 32,768 B
    unsigned short* W3t = (unsigned short*)(ws + 25698304);        // 32,768 B
    int* counts         = (int*)(ws + 25731072);                   // 262,144 B [bin][block]
    int* binsum         = (int*)(ws + 25993216);                   // 1,024 B
    int2* spair         = (int2*)(ws + 25994240);                  // 6,400,000 B -> 32,394,240 total

    setup_kernel<<<256 + CNT_B + OUTZ_B, 256, 0, stream>>>(W1, W2, W3, eidx,
        W1t, Wat, Wbt, W3t, counts, (u32x4*)d_out);
    scanA_kernel<<<NBIN, 256, 0, stream>>>(counts, binsum);
    gemm_scatter_kernel<<<NODE_B + CNT_B, 256, 0, stream>>>(eidx, counts, binsum,
        x, W1t, Wat, Wbt, b1, b2, gA, gB, spair);
    bsort_kernel<<<NBIN, 256, 0, stream>>>(binsum, spair);
    edge_kernel<<<2048, 256, 0, stream>>>(gA, gB, spair, W3t, b3, (unsigned int*)d_out);
}

// Round 14
// 207.355 us; speedup vs baseline: 1.2273x; 1.2273x over previous
//
#include <hip/hip_runtime.h>
#include <hip/hip_bf16.h>

#define N_NODES 50000
#define N_EDGES 800000
#define DIM 128
#define NTILES (N_EDGES / 64)   // 12500 exactly
#define NODE_B 782              // ceil(50000/64)
#define CNT_B 256               // count blocks (LDS hist, no atomics)
#define OUTZ_B 512
#define NBIN 196                // ceil(50000/256) coarse buckets (dst>>8)
#define E_PER_CBLK 3125         // 800000/256
#define CAP 7680                // per-bucket LDS sort capacity (mean 4096, +56 sigma)

typedef __bf16 bf16x8 __attribute__((ext_vector_type(8)));
typedef float f32x4 __attribute__((ext_vector_type(4)));
typedef unsigned int u32x4 __attribute__((ext_vector_type(4)));
typedef short s16x2 __attribute__((ext_vector_type(2)));

__device__ __forceinline__ unsigned short f2bf(float f) {
    unsigned u = __float_as_uint(f);
    u += 0x7fffu + ((u >> 16) & 1u);          // round-to-nearest-even
    return (unsigned short)(u >> 16);
}
__device__ __forceinline__ unsigned short f2bf_hw(float f) {
    __hip_bfloat16 h = __float2bfloat16(f);
    unsigned short s;
    __builtin_memcpy(&s, &h, 2);
    return s;
}
// packed bf16x2 add (v_pk_add_bf16 on gfx950) + relu via packed int16 max
__device__ __forceinline__ unsigned bf2_add_relu(unsigned a, unsigned b) {
    __hip_bfloat162 A, B;
    __builtin_memcpy(&A, &a, 4);
    __builtin_memcpy(&B, &b, 4);
    __hip_bfloat162 S = __hadd2(A, B);
    unsigned s;
    __builtin_memcpy(&s, &S, 4);
    s16x2 sv = __builtin_bit_cast(s16x2, s);
    s16x2 z = (s16x2){0, 0};
    return __builtin_bit_cast(unsigned, __builtin_elementwise_max(sv, z));
}

// ---- K1 (R19-proven): weights (blocks 0..255) + LDS coarse count (256..511) + zero out.
__global__ __launch_bounds__(256) void setup_kernel(
        const float* __restrict__ W1, const float* __restrict__ W2,
        const float* __restrict__ W3, const int* __restrict__ eidx,
        unsigned short* __restrict__ W1t, unsigned short* __restrict__ Wat,
        unsigned short* __restrict__ Wbt, unsigned short* __restrict__ W3t,
        int* __restrict__ counts, u32x4* __restrict__ outz) {
    __shared__ int hh[256];
    int bid = blockIdx.x, tid = threadIdx.x;
    if (bid < 256) {
        int i = bid * 256 + tid;
        int j = i & (DIM * DIM - 1);
        int k = j >> 7, n = j & 127;
        int sec = i >> 14;
        if (sec == 0)      W1t[n * 128 + k] = f2bf(W1[k * 128 + n]);
        else if (sec == 1) Wat[n * 128 + k] = f2bf(W2[k * 128 + n] - W2[(k + 128) * 128 + n]);
        else if (sec == 2) Wbt[n * 128 + k] = f2bf(W2[(k + 128) * 128 + n]);
        else               W3t[n * 128 + k] = f2bf(W3[k * 128 + n]);
    } else if (bid < 512) {
        int cblk = bid - 256;
        hh[tid] = 0;
        __syncthreads();
        int base = cblk * E_PER_CBLK;
        #pragma unroll
        for (int i = 0; i < 13; i++) {
            int idx = i * 256 + tid;
            if (idx < E_PER_CBLK)
                atomicAdd(&hh[eidx[N_EDGES + base + idx] >> 8], 1);
        }
        __syncthreads();
        counts[tid * 256 + cblk] = hh[tid];     // [bin][block]
    } else {
        int b = bid - 512;
        u32x4 z = (u32x4){0u, 0u, 0u, 0u};
        for (int i = b * 256 + tid; i < N_NODES * DIM / 4; i += OUTZ_B * 256) outz[i] = z;
    }
}

// ---- K2 (R18-proven): per-bin exclusive scan over blocks + bin totals.
__global__ void scanA_kernel(int* __restrict__ counts, int* __restrict__ binsum) {
    __shared__ int buf[256];
    int tid = threadIdx.x, b = blockIdx.x;   // b = bin
    int v = counts[b * 256 + tid];
    buf[tid] = v;
    __syncthreads();
    for (int off = 1; off < 256; off <<= 1) {
        int u = (tid >= off) ? buf[tid - off] : 0;
        __syncthreads();
        buf[tid] += u;
        __syncthreads();
    }
    counts[b * 256 + tid] = buf[tid] - v;     // exclusive prefix over blocks
    if (tid == 255) binsum[b] = buf[255];
}

// ---- K3 (R19-proven): node GEMM (blocks 0..781) overlapped with coarse
// scatter (blocks 782..1037). Zero global atomics in scatter.
__global__ __launch_bounds__(256, 2) void gemm_scatter_kernel(
        const int* __restrict__ eidx, const int* __restrict__ counts,
        const int* __restrict__ binsum,
        const float* __restrict__ x, const unsigned short* __restrict__ W1t,
        const unsigned short* __restrict__ Wat, const unsigned short* __restrict__ Wbt,
        const float* __restrict__ b1, const float* __restrict__ b2,
        unsigned short* __restrict__ gA, unsigned short* __restrict__ gB,
        int2* __restrict__ spair) {
    __shared__ __align__(16) unsigned short w1t[128 * 136];
    __shared__ __align__(16) unsigned short h_lds[64 * 136];
    int tid = threadIdx.x, bid = blockIdx.x;

    if (bid >= NODE_B) {
        // ---- coarse scatter into dst>>8 buckets, LDS cursors only
        int blk = bid - NODE_B;
        int* lds = (int*)w1t;                 // [0..255]=scan buf, [256..511]=cursors
        int v = (tid < NBIN) ? binsum[tid] : 0;
        lds[tid] = v;
        __syncthreads();
        for (int off = 1; off < 256; off <<= 1) {
            int u = (tid >= off) ? lds[tid - off] : 0;
            __syncthreads();
            lds[tid] += u;
            __syncthreads();
        }
        int bb = lds[tid] - v;                // exclusive binbase
        __syncthreads();
        lds[256 + tid] = bb + ((tid < NBIN) ? counts[tid * 256 + blk] : 0);
        __syncthreads();
        int* lcur = lds + 256;
        int base = blk * E_PER_CBLK;
        #pragma unroll
        for (int i = 0; i < 13; i++) {
            int idx = i * 256 + tid;
            if (idx < E_PER_CBLK) {
                int e = base + idx;
                int d = eidx[N_EDGES + e];
                int s = eidx[e];
                int p = atomicAdd(&lcur[d >> 8], 1);   // LDS atomic
                spair[p] = make_int2(s, d);
            }
        }
        return;
    }

    // ---- node GEMM (R12-proven): h = bf16(x@W1+b1) -> LDS -> gA, gB
    int bl = bid;
    #pragma unroll
    for (int it = 0; it < 8; it++) {
        int idx = (tid + it * 256) * 8;
        int n = idx >> 7, k = idx & 127;
        *(u32x4*)(&w1t[n * 136 + k]) = *(const u32x4*)(&W1t[idx]);
    }
    int w = tid >> 6, lane = tid & 63;
    int lr = lane & 15, q = lane >> 4;
    bf16x8 baf[2][4], bbf[2][4];
    float b2v[2];
    #pragma unroll
    for (int ct = 0; ct < 2; ct++) {
        int n = (2 * w + ct) * 16 + lr;
        #pragma unroll
        for (int kt = 0; kt < 4; kt++) {
            baf[ct][kt] = __builtin_bit_cast(bf16x8, *(const u32x4*)(&Wat[n * 128 + kt * 32 + q * 8]));
            bbf[ct][kt] = __builtin_bit_cast(bf16x8, *(const u32x4*)(&Wbt[n * 128 + kt * 32 + q * 8]));
        }
        b2v[ct] = b2[n];
    }
    __syncthreads();
    int row0 = bl * 64;
    int rowA = row0 + w * 16 + lr; if (rowA >= N_NODES) rowA = N_NODES - 1;
    {
        f32x4 acc[8];
        #pragma unroll
        for (int ct = 0; ct < 8; ct++) acc[ct] = (f32x4){0.f, 0.f, 0.f, 0.f};
        #pragma unroll
        for (int kt = 0; kt < 4; kt++) {
            const float* ap = x + (size_t)rowA * DIM + kt * 32 + q * 8;
            f32x4 x0 = *(const f32x4*)(ap);
            f32x4 x1 = *(const f32x4*)(ap + 4);
            bf16x8 a;
            #pragma unroll
            for (int j = 0; j < 4; j++) { a[j] = (__bf16)x0[j]; a[j + 4] = (__bf16)x1[j]; }
            #pragma unroll
            for (int ct = 0; ct < 8; ct++) {
                bf16x8 b = __builtin_bit_cast(bf16x8,
                    *(const u32x4*)(&w1t[(ct * 16 + lr) * 136 + kt * 32 + q * 8]));
                acc[ct] = __builtin_amdgcn_mfma_f32_16x16x32_bf16(a, b, acc[ct], 0, 0, 0);
            }
        }
        #pragma unroll
        for (int ct = 0; ct < 8; ct++) {
            int col = ct * 16 + lr;
            float bias = b1[col];
            #pragma unroll
            for (int r = 0; r < 4; r++)   // C/D: col=lane&15, row=quad*4+reg
                h_lds[(w * 16 + q * 4 + r) * 136 + col] = f2bf(acc[ct][r] + bias);
        }
    }
    __syncthreads();
    {
        f32x4 accA[4][2], accB[4][2];
        #pragma unroll
        for (int rt = 0; rt < 4; rt++)
            #pragma unroll
            for (int ct = 0; ct < 2; ct++) {
                accA[rt][ct] = (f32x4){0.f, 0.f, 0.f, 0.f};
                accB[rt][ct] = (f32x4){0.f, 0.f, 0.f, 0.f};
            }
        #pragma unroll
        for (int kt = 0; kt < 4; kt++) {
            #pragma unroll
            for (int rt = 0; rt < 4; rt++) {
                bf16x8 a = __builtin_bit_cast(bf16x8,
                    *(const u32x4*)(&h_lds[(rt * 16 + lr) * 136 + kt * 32 + q * 8]));
                accA[rt][0] = __builtin_amdgcn_mfma_f32_16x16x32_bf16(a, baf[0][kt], accA[rt][0], 0, 0, 0);
                accA[rt][1] = __builtin_amdgcn_mfma_f32_16x16x32_bf16(a, baf[1][kt], accA[rt][1], 0, 0, 0);
                accB[rt][0] = __builtin_amdgcn_mfma_f32_16x16x32_bf16(a, bbf[0][kt], accB[rt][0], 0, 0, 0);
                accB[rt][1] = __builtin_amdgcn_mfma_f32_16x16x32_bf16(a, bbf[1][kt], accB[rt][1], 0, 0, 0);
            }
        }
        #pragma unroll
        for (int rt = 0; rt < 4; rt++) {
            #pragma unroll
            for (int ct = 0; ct < 2; ct++) {
                int col = (2 * w + ct) * 16 + lr;
                #pragma unroll
                for (int r = 0; r < 4; r++) {
                    int row = row0 + rt * 16 + q * 4 + r;
                    if (row < N_NODES) {
                        gA[(size_t)row * DIM + col] = f2bf(accA[rt][ct][r] + b2v[ct]);
                        gB[(size_t)row * DIM + col] = f2bf(accB[rt][ct][r]);
                    }
                }
            }
        }
    }
}

// ---- K4 (R19-proven): per-bucket LDS sort by dst&255, local binbase from binsum.
__global__ __launch_bounds__(256) void bsort_kernel(
        const int* __restrict__ binsum, int2* __restrict__ spair) {
    __shared__ int2 el[CAP];
    __shared__ int h[256];
    __shared__ int cum[256];
    __shared__ int bb[257];
    int tid = threadIdx.x, b = blockIdx.x;
    int v = (tid < NBIN) ? binsum[tid] : 0;
    cum[tid] = v;
    __syncthreads();
    for (int off = 1; off < 256; off <<= 1) {
        int u = (tid >= off) ? cum[tid - off] : 0;
        __syncthreads();
        cum[tid] += u;
        __syncthreads();
    }
    bb[tid] = cum[tid] - v;
    if (tid == 255) bb[256] = cum[255];
    __syncthreads();

    int start = bb[b];
    int n = bb[b + 1] - start;
    int nn = (n < CAP) ? n : CAP;
    for (int i = tid; i < nn; i += 256) el[i] = spair[start + i];
    h[tid] = 0;
    __syncthreads();
    for (int i = tid; i < nn; i += 256) atomicAdd(&h[el[i].y & 255], 1);
    __syncthreads();
    int v2 = h[tid];
    cum[tid] = v2;
    __syncthreads();
    for (int off = 1; off < 256; off <<= 1) {
        int u = (tid >= off) ? cum[tid - off] : 0;
        __syncthreads();
        cum[tid] += u;
        __syncthreads();
    }
    cum[tid] -= v2;                           // exclusive
    __syncthreads();
    for (int i = tid; i < nn; i += 256) {
        int2 e = el[i];
        int p = start + atomicAdd(&cum[e.y & 255], 1);
        spair[p] = e;
    }
}

// ---- K5 (R10-proven, reverted): grid-stride edge kernel (2048 blocks), two LDS
// buffers, 2 barriers/iter, 32-row-group segmax on threads 0..127 with
// interior-segment plain store. R22's 1-barrier wave-local variant regressed
// (bank conflicts 3x, atomics 2x, occupancy -10pts) — this geometry is proven.
__global__ __launch_bounds__(256, 3) void edge_kernel(
        const unsigned short* __restrict__ gA,
        const unsigned short* __restrict__ gB,
        const int2* __restrict__ spair,
        const unsigned short* __restrict__ W3t,
        const float* __restrict__ b3,
        unsigned int* __restrict__ out) {
    __shared__ __align__(16) unsigned short m1_lds[64 * 136];
    __shared__ __align__(16) unsigned short m2_lds[64 * 136];
    __shared__ int s_dst[2][64];

    int tid = threadIdx.x;
    int w = tid >> 6, lane = tid & 63;
    int lr = lane & 15, q = lane >> 4;
    int tr = tid >> 4;
    int c = (tid & 15) * 8;

    bf16x8 b3f[2][4];
    float b3v[2];
    #pragma unroll
    for (int ct = 0; ct < 2; ct++) {
        int n = (2 * w + ct) * 16 + lr;
        #pragma unroll
        for (int kt = 0; kt < 4; kt++)
            b3f[ct][kt] = __builtin_bit_cast(bf16x8, *(const u32x4*)(&W3t[n * 128 + kt * 32 + q * 8]));
        b3v[ct] = b3[n];
    }

    const int G = (int)gridDim.x;
    int tb = blockIdx.x;
    int sel = 0;

    int2 pcur[4];
    u32x4 gb_r[4];
    {
        int eb = tb * 64;
        #pragma unroll
        for (int it = 0; it < 4; it++) pcur[it] = spair[eb + tr + 16 * it];
        #pragma unroll
        for (int it = 0; it < 4; it++)
            gb_r[it] = *(const u32x4*)(&gB[(size_t)pcur[it].x * DIM + c]);
    }

    for (; tb < NTILES; tb += G) {
        #pragma unroll
        for (int it = 0; it < 4; it++) {
            int t = tr + 16 * it;
            u32x4 ga = *(const u32x4*)(&gA[(size_t)pcur[it].y * DIM + c]);
            u32x4 m;
            #pragma unroll
            for (int jj = 0; jj < 4; jj++)
                m[jj] = bf2_add_relu(ga[jj], gb_r[it][jj]);
            *(u32x4*)(&m1_lds[t * 136 + c]) = m;
        }
        if ((tid & 15) == 0) {
            #pragma unroll
            for (int it = 0; it < 4; it++) s_dst[sel][tr + 16 * it] = pcur[it].y;
        }
        __syncthreads();   // (1) m1 + s_dst ready; also orders segmax(t-1) before m2 writes(t)

        int nx = tb + G;
        int2 pnx[4];
        if (nx < NTILES) {
            int eb = nx * 64;
            #pragma unroll
            for (int it = 0; it < 4; it++) pnx[it] = spair[eb + tr + 16 * it];
            #pragma unroll
            for (int it = 0; it < 4; it++)
                gb_r[it] = *(const u32x4*)(&gB[(size_t)pnx[it].x * DIM + c]);
        }

        f32x4 acc2[4][2];
        #pragma unroll
        for (int rt = 0; rt < 4; rt++)
            #pragma unroll
            for (int ct = 0; ct < 2; ct++) acc2[rt][ct] = (f32x4){0.f, 0.f, 0.f, 0.f};
        #pragma unroll
        for (int kt = 0; kt < 4; kt++) {
            #pragma unroll
            for (int rt = 0; rt < 4; rt++) {
                bf16x8 a = __builtin_bit_cast(bf16x8,
                    *(const u32x4*)(&m1_lds[(rt * 16 + lr) * 136 + kt * 32 + q * 8]));
                acc2[rt][0] = __builtin_amdgcn_mfma_f32_16x16x32_bf16(a, b3f[0][kt], acc2[rt][0], 0, 0, 0);
                acc2[rt][1] = __builtin_amdgcn_mfma_f32_16x16x32_bf16(a, b3f[1][kt], acc2[rt][1], 0, 0, 0);
            }
        }
        #pragma unroll
        for (int rt = 0; rt < 4; rt++) {
            #pragma unroll
            for (int ct = 0; ct < 2; ct++) {
                int col = (2 * w + ct) * 16 + lr;
                #pragma unroll
                for (int r = 0; r < 4; r++)
                    m2_lds[(rt * 16 + q * 4 + r) * 136 + col] = f2bf_hw(fmaxf(acc2[rt][ct][r] + b3v[ct], 0.f));
            }
        }
        __syncthreads();   // (2) m2 ready

        if (tid < 128) {
            int pair = tid & 63;
            int g = tid >> 6;                           // == wave index (0 or 1)
            const unsigned* m2p = (const unsigned*)m2_lds;   // [64][68] dwords
            int r0 = g * 32;
            unsigned cur = m2p[r0 * 68 + pair];
            int d = s_dst[sel][r0];                     // wave-uniform
            bool first = true;                          // first segment may extend before r0
            #pragma unroll 4
            for (int i = 1; i < 32; i++) {
                int dn = s_dst[sel][r0 + i];            // wave-uniform
                unsigned v = m2p[(r0 + i) * 68 + pair];
                if (dn != d) {                          // wave-uniform branch
                    if (first) {
                        atomicMax(&out[(size_t)d * DIM + 2 * pair],     (cur & 0xffffu) << 16);
                        atomicMax(&out[(size_t)d * DIM + 2 * pair + 1], cur & 0xffff0000u);
                    } else {
                        // interior segment: unique writer -> plain coalesced 8B store
                        uint2 st = make_uint2((cur & 0xffffu) << 16, cur & 0xffff0000u);
                        *(uint2*)(&out[(size_t)d * DIM + 2 * pair]) = st;
                    }
                    first = false;
                    d = dn; cur = v;
                } else {
                    s16x2 a2 = __builtin_bit_cast(s16x2, cur);
                    s16x2 b2 = __builtin_bit_cast(s16x2, v);
                    cur = __builtin_bit_cast(unsigned, __builtin_elementwise_max(a2, b2));
                }
            }
            // last segment may extend past r0+31 -> always atomic
            atomicMax(&out[(size_t)d * DIM + 2 * pair],     (cur & 0xffffu) << 16);
            atomicMax(&out[(size_t)d * DIM + 2 * pair + 1], cur & 0xffff0000u);
        }
        // no trailing barrier: next iter's m1/s_dst[sel^1] writes don't touch m2/s_dst[sel];
        // waves 2-3 run ahead into the next staging while waves 0-1 finish segmax.

        sel ^= 1;
        #pragma unroll
        for (int it = 0; it < 4; it++) pcur[it] = pnx[it];
    }
}

extern "C" void kernel_launch(void* const* d_in, const int* in_sizes, int n_in,
                              void* d_out, int out_size, void* d_ws, size_t ws_size,
                              hipStream_t stream) {
    const float* x  = (const float*)d_in[0];
    const int* eidx = (const int*)d_in[1];
    const float* W1 = (const float*)d_in[2];
    const float* b1 = (const float*)d_in[3];
    const float* W2 = (const float*)d_in[4];
    const float* b2 = (const float*)d_in[5];
    const float* W3 = (const float*)d_in[6];
    const float* b3 = (const float*)d_in[7];

    char* ws = (char*)d_ws;
    unsigned short* gA  = (unsigned short*)ws;                     // 12,800,000 B
    unsigned short* gB  = (unsigned short*)(ws + 12800000);        // 12,800,000 B
    unsigned short* W1t = (unsigned short*)(ws + 25600000);        // 32,768 B
    unsigned short* Wat = (unsigned short*)(ws + 25632768);        // 32,768 B
    unsigned short* Wbt = (unsigned short*)(ws + 25665536);        // 32,768 B
    unsigned short* W3t = (unsigned short*)(ws + 25698304);        // 32,768 B
    int* counts         = (int*)(ws + 25731072);                   // 262,144 B [bin][block]
    int* binsum         = (int*)(ws + 25993216);                   // 1,024 B
    int2* spair         = (int2*)(ws + 25994240);                  // 6,400,000 B -> 32,394,240 total

    setup_kernel<<<256 + CNT_B + OUTZ_B, 256, 0, stream>>>(W1, W2, W3, eidx,
        W1t, Wat, Wbt, W3t, counts, (u32x4*)d_out);
    scanA_kernel<<<NBIN, 256, 0, stream>>>(counts, binsum);
    gemm_scatter_kernel<<<NODE_B + CNT_B, 256, 0, stream>>>(eidx, counts, binsum,
        x, W1t, Wat, Wbt, b1, b2, gA, gB, spair);
    bsort_kernel<<<NBIN, 256, 0, stream>>>(binsum, spair);
    edge_kernel<<<2048, 256, 0, stream>>>(gA, gB, spair, W3t, b3, (unsigned int*)d_out);
}